// Round 9
// baseline (196.370 us; speedup 1.0000x reference)
//
#include <hip/hip_runtime.h>
#include <hip/hip_bf16.h>
#include <hip/hip_fp8.h>

#define DIN   128
#define DH    128
#define DOUTC 64
#define BN_EPS 1e-5f

typedef __attribute__((ext_vector_type(8))) short bf16x8;
typedef __attribute__((ext_vector_type(4))) float f32x4;
typedef __attribute__((ext_vector_type(2))) float f32x2;

#ifndef __has_builtin
#define __has_builtin(x) 0
#endif
#if __has_builtin(__builtin_amdgcn_cvt_pk_f32_fp8) && __has_builtin(__builtin_amdgcn_cvt_pk_fp8_f32)
#define HW_FP8 1
#else
#define HW_FP8 0
#endif

__device__ inline unsigned short f2bf(float f) {
    __hip_bfloat16 b = __float2bfloat16(f);
    return *reinterpret_cast<unsigned short*>(&b);
}
__device__ inline float bf2f(unsigned short u) {
    return __uint_as_float(((unsigned int)u) << 16);
}
__device__ inline void fp8x4_to_f32(unsigned int w, float* o) {
#if HW_FP8
    f32x2 lo = __builtin_amdgcn_cvt_pk_f32_fp8((int)w, false);
    f32x2 hi = __builtin_amdgcn_cvt_pk_f32_fp8((int)w, true);
    o[0] = lo.x; o[1] = lo.y; o[2] = hi.x; o[3] = hi.y;
#else
    #pragma unroll
    for (int c = 0; c < 4; ++c) {
        __hip_fp8_e4m3 q; q.__x = (__hip_fp8_storage_t)((w >> (8 * c)) & 0xFF);
        o[c] = (float)q;
    }
#endif
}
__device__ inline unsigned int f32x4_to_fp8(float a, float b, float c, float d) {
#if HW_FP8
    int p = __builtin_amdgcn_cvt_pk_fp8_f32(a, b, 0, false);
    p = __builtin_amdgcn_cvt_pk_fp8_f32(c, d, p, true);
    return (unsigned int)p;
#else
    __hip_fp8_e4m3 qa(a), qb(b), qc(c), qd(d);
    return (unsigned int)qa.__x | ((unsigned int)qb.__x << 8) |
           ((unsigned int)qc.__x << 16) | ((unsigned int)qd.__x << 24);
#endif
}

// ---------------------------------------------------------------------------
// Exclusive prefix scan over 256 LDS ints (all 256 threads must call).
// ---------------------------------------------------------------------------
__device__ inline void block_excl_scan_256(const int* __restrict__ arr,
                                           int* __restrict__ excl,
                                           int* __restrict__ wsum, int tid)
{
    int lane = tid & 63, w = tid >> 6;
    int v = arr[tid];
    int inc = v;
    #pragma unroll
    for (int off = 1; off < 64; off <<= 1) {
        int t = __shfl_up(inc, off, 64);
        if (lane >= off) inc += t;
    }
    if (lane == 63) wsum[w] = inc;
    __syncthreads();
    if (tid == 0) {
        int s = 0;
        #pragma unroll
        for (int i = 0; i < 4; ++i) { int t = wsum[i]; wsum[i] = s; s += t; }
    }
    __syncthreads();
    excl[tid] = inc - v + wsum[w];
    __syncthreads();
}

// ---------------------------------------------------------------------------
// prep_kernel — three independent block ranges:
//   [0, cvtB)              : x -> xq (fp8 e4m3) AND xb (bf16)
//   [cvtB, cvtB+192)       : pack Wl1 / Wr1 / [Wl2|Wr2] into MFMA B-frag order
//   [cvtB+192, ...)        : bin_coarse — counting-sort pass A (dst>>8)
// ---------------------------------------------------------------------------
__global__ __launch_bounds__(256) void prep_kernel(
    const float* __restrict__ x, unsigned char* __restrict__ xq,
    unsigned short* __restrict__ xb,
    const float* __restrict__ Wl1, const float* __restrict__ Wr1,
    const float* __restrict__ Wl2, const float* __restrict__ Wr2,
    unsigned short* __restrict__ W1p, unsigned short* __restrict__ W2p,
    const int* __restrict__ ei, int* __restrict__ cursor,
    unsigned int* __restrict__ coarse,
    int total8, int cvtB, int E, int nb, int cap)
{
    __shared__ int hist[256], lstart[256], gbase[256], wsum[4];
    __shared__ unsigned int staged[4096];
    const int b = blockIdx.x;
    const int tid = threadIdx.x;

    if (b < cvtB) {
        int i = b * 256 + tid;
        if (i >= total8) return;
        float4 a = ((const float4*)x)[2 * i];
        float4 c = ((const float4*)x)[2 * i + 1];
        uint2 pk;
        pk.x = f32x4_to_fp8(a.x, a.y, a.z, a.w);
        pk.y = f32x4_to_fp8(c.x, c.y, c.z, c.w);
        *(uint2*)(xq + (size_t)i * 8) = pk;
        unsigned short t8[8];
        t8[0]=f2bf(a.x); t8[1]=f2bf(a.y); t8[2]=f2bf(a.z); t8[3]=f2bf(a.w);
        t8[4]=f2bf(c.x); t8[5]=f2bf(c.y); t8[6]=f2bf(c.z); t8[7]=f2bf(c.w);
        *(uint4*)(xb + (size_t)i * 8) = *(uint4*)t8;
        return;
    }
    if (b < cvtB + 192) {
        int region = (b - cvtB) >> 6;
        int idx = ((b - cvtB) & 63) * 256 + tid;   // 0..16383
        int k = idx >> 7, c = idx & 127;
        int d = ((k >> 5) * 8 + (c >> 4)) * 512 + ((k >> 3) & 3) * 128 + (c & 15) * 8 + (k & 7);
        if (region == 0)      W1p[d] = f2bf(Wl1[idx]);
        else if (region == 1) W1p[128 * 128 + d] = f2bf(Wr1[idx]);
        else {
            float v = (c < 64) ? Wl2[k * 64 + c] : Wr2[k * 64 + (c - 64)];
            W2p[d] = f2bf(v);
        }
        return;
    }

    // ---- bin_coarse ----
    const int chunkBase = (b - cvtB - 192) * 4096;
    hist[tid] = 0;
    __syncthreads();

    unsigned int rec[16]; int pos[16]; int bb[16];
    #pragma unroll
    for (int i = 0; i < 16; ++i) {
        int e = chunkBase + i * 256 + tid;
        if (e < E) {
            int s = ei[e], d = ei[E + e];
            rec[i] = ((unsigned int)d << 16) | (unsigned int)s;
            bb[i]  = d >> 8;
            pos[i] = atomicAdd(&hist[bb[i]], 1);
        } else bb[i] = -1;
    }
    __syncthreads();

    block_excl_scan_256(hist, lstart, wsum, tid);

    if (tid < nb) {
        int c = hist[tid];
        gbase[tid] = c ? atomicAdd(&cursor[tid], c) : 0;
    }
    __syncthreads();

    #pragma unroll
    for (int i = 0; i < 16; ++i)
        if (bb[i] >= 0) staged[lstart[bb[i]] + pos[i]] = rec[i];
    __syncthreads();

    int total = min(4096, E - chunkBase);
    for (int i = tid; i < total; i += 256) {
        unsigned int r = staged[i];
        int bk  = (int)(r >> 24);
        int gp  = gbase[bk] + (i - lstart[bk]);
        if (gp < cap) coarse[(size_t)bk * cap + gp] = r;
    }
}

// ---------------------------------------------------------------------------
// Counting sort pass B: one block per coarse bucket; scatter src (ushort)
// into bucket-owned window; emit deg / row_start.
// ---------------------------------------------------------------------------
__global__ __launch_bounds__(256) void bin_fine(
    const int* __restrict__ cursor, const unsigned int* __restrict__ coarse,
    unsigned short* __restrict__ sorted, int* __restrict__ deg,
    int* __restrict__ row_start, int n, int cap)
{
    __shared__ int hist[256], pstart[256], cur2[256], wsum[4];
    const int b = blockIdx.x, tid = threadIdx.x;
    const int cnt = min(cursor[b], cap);
    const unsigned int* src = coarse + (size_t)b * cap;

    hist[tid] = 0;
    __syncthreads();

    int nIter = (cnt + 255) >> 8;
    for (int i = 0; i < nIter; ++i) {
        int idx = i * 256 + tid;
        if (idx < cnt) atomicAdd(&hist[(src[idx] >> 16) & 255], 1);
    }
    __syncthreads();

    block_excl_scan_256(hist, pstart, wsum, tid);
    cur2[tid] = pstart[tid];
    __syncthreads();

    for (int i = 0; i < nIter; ++i) {
        int idx = i * 256 + tid;
        if (idx < cnt) {
            unsigned int r = src[idx];
            int dl = (r >> 16) & 255;
            int p  = atomicAdd(&cur2[dl], 1);
            sorted[(size_t)b * cap + p] = (unsigned short)(r & 0xFFFFu);
        }
    }

    int node = b * 256 + tid;
    if (node < n) {
        deg[node]       = hist[tid];
        row_start[node] = b * cap + pstart[tid];
    }
}

// ---------------------------------------------------------------------------
// GEMM1 fused with layer-1 gather — R4 structure (best measured).
//   32-row tiles, 1563 blocks. Each of 4 waves gathers 8 rows (8 lanes/row,
//   16B uint4/lane), tail-free masked batches of 8 + index prefetch; then
//   computes a 16-row x 64-col output quadrant (rg = wave>>1, ch = wave&1).
//   Wr-path A-frags read from pre-converted bf16 xb. BN partials: ROW-MAJOR
//   bn_part[blk][256].
// ---------------------------------------------------------------------------
__global__ __launch_bounds__(256) void gemm1_fused(
    const unsigned char* __restrict__ xq, const unsigned short* __restrict__ xb,
    const int* __restrict__ row_start, const int* __restrict__ deg,
    const unsigned short* __restrict__ sorted,
    const unsigned short* __restrict__ W1p, const float* __restrict__ bias,
    unsigned short* __restrict__ hb,
    float* __restrict__ bn_part, int n)
{
    __shared__ unsigned short G[32][136];
    __shared__ float red[2][2][128];

    const int block_row = blockIdx.x * 32;
    const int tid  = threadIdx.x;
    const int wave = tid >> 6;
    const int lane = tid & 63;
    const int q    = lane >> 4;
    const int m16  = lane & 15;
    const int rg   = wave >> 1;      // row group (16 rows)
    const int ch   = wave & 1;       // column half (64 cols)

    // ---- gather this wave's 8 rows into G ----
    {
        int sub = lane & 7, oct = lane >> 3;
        int lr = rg * 16 + ch * 8 + oct;
        int g  = block_row + lr;
        float acc[16];
        #pragma unroll
        for (int j = 0; j < 16; ++j) acc[j] = 0.f;
        int d = 0, base = 0;
        if (g < n) { base = row_start[g]; d = deg[g]; }
        int nb8 = (d + 7) >> 3;            // masked full batches, no tail
        int si[8];
        if (nb8 > 0) {
            #pragma unroll
            for (int u = 0; u < 8; ++u)
                si[u] = (int)sorted[base + (u < d ? u : 0)];
        }
        for (int b = 0; b < nb8; ++b) {
            uint4 raws[8];
            #pragma unroll
            for (int u = 0; u < 8; ++u)
                raws[u] = ((const uint4*)(xq + (size_t)si[u] * DIN))[sub];
            // prefetch next batch's indices while gathers are in flight
            if (b + 1 < nb8) {
                int t0n = (b + 1) * 8;
                #pragma unroll
                for (int u = 0; u < 8; ++u) {
                    int tt = t0n + u;
                    si[u] = (int)sorted[base + (tt < d ? tt : 0)];
                }
            }
            int t0 = b * 8;
            #pragma unroll
            for (int u = 0; u < 8; ++u) {
                float w8 = (t0 + u < d) ? 1.0f : 0.0f;
                const unsigned int* w = (const unsigned int*)&raws[u];
                #pragma unroll
                for (int c = 0; c < 4; ++c) {
                    float o4[4];
                    fp8x4_to_f32(w[c], o4);
                    acc[c*4+0] = fmaf(o4[0], w8, acc[c*4+0]);
                    acc[c*4+1] = fmaf(o4[1], w8, acc[c*4+1]);
                    acc[c*4+2] = fmaf(o4[2], w8, acc[c*4+2]);
                    acc[c*4+3] = fmaf(o4[3], w8, acc[c*4+3]);
                }
            }
        }
        float inv = 1.0f / fmaxf((float)d, 1.0f);
        unsigned short t16[16];
        #pragma unroll
        for (int j = 0; j < 16; ++j) t16[j] = f2bf(acc[j] * inv);
        *(uint4*)&G[lr][sub * 16]     = ((uint4*)t16)[0];
        *(uint4*)&G[lr][sub * 16 + 8] = ((uint4*)t16)[1];
    }
    __syncthreads();   // MFMA reads 16 rows written by two waves

    f32x4 acc[4];
    #pragma unroll
    for (int nt = 0; nt < 4; ++nt) acc[nt] = (f32x4){0.f, 0.f, 0.f, 0.f};

    const int grow = block_row + rg * 16 + m16;   // this lane's A row
    #pragma unroll
    for (int ks = 0; ks < 4; ++ks) {
        bf16x8 ag = *(const bf16x8*)&G[rg * 16 + m16][ks * 32 + q * 8];
        const unsigned short* wp0 = W1p + (size_t)ks * 8 * 512 + (size_t)ch * 4 * 512;   // Wl1
        #pragma unroll
        for (int nt = 0; nt < 4; ++nt) {
            bf16x8 b = *(const bf16x8*)(wp0 + nt * 512 + lane * 8);
            acc[nt] = __builtin_amdgcn_mfma_f32_16x16x32_bf16(ag, b, acc[nt], 0, 0, 0);
        }
        // X frag: direct bf16 load from xb (pre-converted in prep)
        uint4 raw = make_uint4(0u, 0u, 0u, 0u);
        if (grow < n)
            raw = *(const uint4*)(xb + (size_t)grow * DIN + ks * 32 + q * 8);
        bf16x8 ax = *(bf16x8*)&raw;
        const unsigned short* wp1 = W1p + (size_t)(4 + ks) * 8 * 512 + (size_t)ch * 4 * 512; // Wr1
        #pragma unroll
        for (int nt = 0; nt < 4; ++nt) {
            bf16x8 b = *(const bf16x8*)(wp1 + nt * 512 + lane * 8);
            acc[nt] = __builtin_amdgcn_mfma_f32_16x16x32_bf16(ax, b, acc[nt], 0, 0, 0);
        }
    }

    // ---- epilogue: bias, hb store, BN partials (row-major bn_part) ----
    float psum[4], psq[4];
    #pragma unroll
    for (int nt = 0; nt < 4; ++nt) {
        int col = (ch * 4 + nt) * 16 + m16;
        float bv = bias[col];
        float s = 0.f, ssq = 0.f;
        #pragma unroll
        for (int reg = 0; reg < 4; ++reg) {
            int g = block_row + rg * 16 + q * 4 + reg;
            float v = acc[nt][reg] + bv;
            if (g < n) {
                hb[(size_t)g * DH + col] = f2bf(v);
                s += v; ssq += v * v;
            }
        }
        psum[nt] = s; psq[nt] = ssq;
    }
    #pragma unroll
    for (int nt = 0; nt < 4; ++nt) {
        psum[nt] += __shfl_xor(psum[nt], 16, 64);
        psum[nt] += __shfl_xor(psum[nt], 32, 64);
        psq[nt]  += __shfl_xor(psq[nt], 16, 64);
        psq[nt]  += __shfl_xor(psq[nt], 32, 64);
    }
    if (lane < 16) {
        #pragma unroll
        for (int nt = 0; nt < 4; ++nt) {
            red[0][rg][(ch * 4 + nt) * 16 + lane] = psum[nt];
            red[1][rg][(ch * 4 + nt) * 16 + lane] = psq[nt];
        }
    }
    __syncthreads();
    if (tid < 128) {
        float s   = red[0][0][tid] + red[0][1][tid];
        float ssq = red[1][0][tid] + red[1][1][tid];
        bn_part[(size_t)blockIdx.x * 256 + tid]       = s;
        bn_part[(size_t)blockIdx.x * 256 + 128 + tid] = ssq;
    }
}

// ---------------------------------------------------------------------------
// bn_reduce: 64 blocks; block j sums rows j, j+64, ... of bn_part[nblk][256]
// (coalesced 1KB rows) and atomicAdds its 256 column partials into
// bn_out[256] (= bn_sum[128] ++ bn_sumsq[128], zero-initialized).
// ---------------------------------------------------------------------------
__global__ __launch_bounds__(256) void bn_reduce(
    const float* __restrict__ bn_part, float* __restrict__ bn_out, int nblk)
{
    const int tid = threadIdx.x;
    float s = 0.f;
    for (int r = blockIdx.x; r < nblk; r += 64)
        s += bn_part[(size_t)r * 256 + tid];
    atomicAdd(&bn_out[tid], s);
}

// ---------------------------------------------------------------------------
// GEMM2 (MFMA bf16): BN finalize in LDS; A-frags loaded directly from hb and
// BN+ReLU applied in registers (no LDS A tile).
// cols 0..63 -> P = a@Wl2 (bf16), cols 64..127 -> out = a@Wr2 + b2 (fp32).
// ---------------------------------------------------------------------------
__global__ __launch_bounds__(256) void gemm2p_mfma(
    const unsigned short* __restrict__ hb,
    const float* __restrict__ bn_sum, const float* __restrict__ bn_sumsq,
    const float* __restrict__ gamma, const float* __restrict__ beta,
    const unsigned short* __restrict__ W2p, const float* __restrict__ bias,
    unsigned short* __restrict__ P, float* __restrict__ out, int n)
{
    __shared__ float s_scale[128], s_shift[128];

    const int block_row = blockIdx.x * 64;
    const int tid  = threadIdx.x;
    const int wave = tid >> 6;
    const int lane = tid & 63;
    const int q    = lane >> 4;
    const int m16  = lane & 15;

    if (tid < 128) {
        float invN = 1.0f / (float)n;
        float mu  = bn_sum[tid] * invN;
        float var = bn_sumsq[tid] * invN - mu * mu;
        float sc  = gamma[tid] * rsqrtf(var + BN_EPS);
        s_scale[tid] = sc;
        s_shift[tid] = beta[tid] - mu * sc;
    }
    __syncthreads();

    f32x4 acc[8];
    #pragma unroll
    for (int nt = 0; nt < 8; ++nt) acc[nt] = (f32x4){0.f, 0.f, 0.f, 0.f};

    const int grow = block_row + wave * 16 + m16;
    #pragma unroll
    for (int ks = 0; ks < 4; ++ks) {
        bf16x8 a;
        {
            int kbase = ks * 32 + q * 8;
            float4 sc0 = *(const float4*)&s_scale[kbase];
            float4 sc1 = *(const float4*)&s_scale[kbase + 4];
            float4 sh0 = *(const float4*)&s_shift[kbase];
            float4 sh1 = *(const float4*)&s_shift[kbase + 4];
            unsigned short t[8] = {0,0,0,0,0,0,0,0};
            if (grow < n) {
                uint4 raw = *(const uint4*)(hb + (size_t)grow * DH + kbase);
                const unsigned short* u = (const unsigned short*)&raw;
                t[0] = f2bf(fmaxf(bf2f(u[0]) * sc0.x + sh0.x, 0.f));
                t[1] = f2bf(fmaxf(bf2f(u[1]) * sc0.y + sh0.y, 0.f));
                t[2] = f2bf(fmaxf(bf2f(u[2]) * sc0.z + sh0.z, 0.f));
                t[3] = f2bf(fmaxf(bf2f(u[3]) * sc0.w + sh0.w, 0.f));
                t[4] = f2bf(fmaxf(bf2f(u[4]) * sc1.x + sh1.x, 0.f));
                t[5] = f2bf(fmaxf(bf2f(u[5]) * sc1.y + sh1.y, 0.f));
                t[6] = f2bf(fmaxf(bf2f(u[6]) * sc1.z + sh1.z, 0.f));
                t[7] = f2bf(fmaxf(bf2f(u[7]) * sc1.w + sh1.w, 0.f));
            }
            a = *(bf16x8*)t;
        }
        const unsigned short* wp = W2p + (size_t)ks * 8 * 512;
        #pragma unroll
        for (int nt = 0; nt < 8; ++nt) {
            bf16x8 b = *(const bf16x8*)(wp + nt * 512 + lane * 8);
            acc[nt] = __builtin_amdgcn_mfma_f32_16x16x32_bf16(a, b, acc[nt], 0, 0, 0);
        }
    }

    #pragma unroll
    for (int nt = 0; nt < 4; ++nt) {
        int col = nt * 16 + m16;
        #pragma unroll
        for (int reg = 0; reg < 4; ++reg) {
            int g = block_row + wave * 16 + q * 4 + reg;
            if (g < n) P[(size_t)g * DOUTC + col] = f2bf(acc[nt][reg]);
        }
    }
    #pragma unroll
    for (int nt = 4; nt < 8; ++nt) {
        int col = (nt - 4) * 16 + m16;
        float bv = bias[col];
        #pragma unroll
        for (int reg = 0; reg < 4; ++reg) {
            int g = block_row + wave * 16 + q * 4 + reg;
            if (g < n) out[(size_t)g * DOUTC + col] = acc[nt][reg] + bv;
        }
    }
}

// ---------------------------------------------------------------------------
// Layer-2 gather-mean over bf16 P rows — BATCH-16 via 16 lanes/row (uint2
// 8B/lane): mean degree = 16, so the typical row completes in ONE memory
// round trip (batch-8 needed 2-3). Registers stay ~60 (raws[16] as uint2 =
// 32 VGPR, vs 64 for the uint4 variant that regressed in R2). 4 rows/wave,
// 3125 blocks. Coalescing: lanes 0-15 share a row -> contiguous 128B.
// ---------------------------------------------------------------------------
__global__ __launch_bounds__(256) void agg_gather64_add(
    const int* __restrict__ row_start, const int* __restrict__ deg,
    const unsigned short* __restrict__ sorted, const unsigned short* __restrict__ P,
    float* __restrict__ out, int n)
{
    int wid  = (blockIdx.x * 256 + threadIdx.x) >> 6;
    int lane = threadIdx.x & 63;
    int sub = lane & 15, rr = lane >> 4;
    int r = wid * 4 + rr;
    if (r >= n) return;

    float acc[4];
    #pragma unroll
    for (int j = 0; j < 4; ++j) acc[j] = 0.f;

    int base = row_start[r];
    int d    = deg[r];
    int nb16 = (d + 15) >> 4;
    int si[16];
    if (nb16 > 0) {
        #pragma unroll
        for (int u = 0; u < 16; ++u)
            si[u] = (int)sorted[base + (u < d ? u : 0)];
    }
    for (int b = 0; b < nb16; ++b) {
        uint2 raws[16];
        #pragma unroll
        for (int u = 0; u < 16; ++u)
            raws[u] = ((const uint2*)(P + (size_t)si[u] * DOUTC))[sub];
        if (b + 1 < nb16) {
            int tb = (b + 1) * 16;
            #pragma unroll
            for (int u = 0; u < 16; ++u) {
                int tt = tb + u;
                si[u] = (int)sorted[base + (tt < d ? tt : 0)];
            }
        }
        int t0 = b * 16;
        #pragma unroll
        for (int u = 0; u < 16; ++u) {
            float w8 = (t0 + u < d) ? 1.0f : 0.0f;
            const unsigned short* us = (const unsigned short*)&raws[u];
            #pragma unroll
            for (int j = 0; j < 4; ++j) acc[j] = fmaf(bf2f(us[j]), w8, acc[j]);
        }
    }
    float inv = 1.0f / fmaxf((float)d, 1.0f);
    float* op = out + (size_t)r * DOUTC + sub * 4;
    float4 c0 = *(float4*)op;
    c0.x += acc[0] * inv; c0.y += acc[1] * inv;
    c0.z += acc[2] * inv; c0.w += acc[3] * inv;
    *(float4*)op = c0;
}

// ---------------------------------------------------------------------------
extern "C" void kernel_launch(void* const* d_in, const int* in_sizes, int n_in,
                              void* d_out, int out_size, void* d_ws, size_t ws_size,
                              hipStream_t stream)
{
    const float* x     = (const float*)d_in[0];
    const int*   ei    = (const int*)  d_in[1];
    const float* Wl1   = (const float*)d_in[2];
    const float* Wr1   = (const float*)d_in[3];
    const float* b1    = (const float*)d_in[4];
    const float* gamma = (const float*)d_in[5];
    const float* beta  = (const float*)d_in[6];
    const float* Wl2   = (const float*)d_in[7];
    const float* Wr2   = (const float*)d_in[8];
    const float* b2    = (const float*)d_in[9];
    float*       out   = (float*)d_out;

    const int N = in_sizes[0] / DIN;      // 50000
    const int E = in_sizes[1] / 2;        // 800000

    const int NB  = (N + 255) >> 8;                       // coarse buckets
    int cap = (E / NB) * 3 / 2 + 256;
    cap = (cap + 255) & ~255;

    const int gemm1_blocks = (N + 31) / 32;               // 32-row tiles
    const int gemm2_blocks = (N + 63) / 64;

    // workspace layout (segments 16B-aligned-ish; all 4B aligned)
    float* bn_sum   = (float*)d_ws;                       // 128
    float* bn_sumsq = bn_sum + DH;                        // 128
    int* cursor     = (int*)(bn_sumsq + DH);              // 256
    int* deg        = cursor + 256;                       // N
    int* row_start  = deg + N;                            // N
    unsigned int* coarse   = (unsigned int*)(row_start + N);            // NB*cap
    unsigned short* sorted = (unsigned short*)(coarse + (size_t)NB * cap);
    unsigned short* hb     = sorted + (size_t)NB * cap;   // N*128 bf16
    unsigned short* P      = hb + (size_t)N * DH;         // N*64 bf16
    unsigned short* W1p    = P + (size_t)N * DOUTC;       // 256*128 bf16
    unsigned short* W2p    = W1p + 256 * 128;             // 128*128 bf16
    unsigned short* xb     = W2p + 128 * 128;             // N*128 bf16
    unsigned char*  xq     = (unsigned char*)(xb + (size_t)N * DIN); // N*128 fp8
    float* bn_part  = (float*)(xq + (size_t)N * DIN);     // gemm1_blocks*256

    // zero bn sums + coarse cursors (contiguous)
    hipMemsetAsync(bn_sum, 0, (2 * DH + 256) * sizeof(float), stream);

    dim3 blk(256);
    const int cvtB        = (N * DIN / 8 + 255) / 256;        // 3125
    const int binA_blocks = (E + 4095) / 4096;                // 196
    const int g64_blocks  = (N + 15) / 16;                    // 4 rows/wave x 4 waves

    // ---- prep: x-quantize(+bf16) | weight-pack | coarse-bin (one launch) ----
    prep_kernel<<<cvtB + 192 + binA_blocks, blk, 0, stream>>>(
        x, xq, xb, Wl1, Wr1, Wl2, Wr2, W1p, W2p,
        ei, cursor, coarse, N * DIN / 8, cvtB, E, NB, cap);

    // ---- counting sort pass B ----
    bin_fine<<<NB, blk, 0, stream>>>(cursor, coarse, sorted, deg, row_start, N, cap);

    // ---- layer 1: fused gather + GEMM + BN partials ----
    gemm1_fused<<<gemm1_blocks, blk, 0, stream>>>(xq, xb, row_start, deg, sorted,
                                                  W1p, b1, hb, bn_part, N);

    // ---- BN partial reduction (coalesced rows, spread atomics) ----
    bn_reduce<<<64, blk, 0, stream>>>(bn_part, bn_sum, gemm1_blocks);

    // ---- layer 2: BN finalize + ReLU + project ----
    gemm2p_mfma<<<gemm2_blocks, blk, 0, stream>>>(hb, bn_sum, bn_sumsq,
                                                  gamma, beta, W2p, b2, P, out, N);

    // ---- layer 2 aggregation ----
    agg_gather64_add<<<g64_blocks, blk, 0, stream>>>(row_start, deg, sorted,
                                                     P, out, N);
}

// Round 10
// 185.580 us; speedup vs baseline: 1.0581x; 1.0581x over previous
//
#include <hip/hip_runtime.h>
#include <hip/hip_bf16.h>
#include <hip/hip_fp8.h>

#define DIN   128
#define DH    128
#define DOUTC 64
#define BN_EPS 1e-5f

typedef __attribute__((ext_vector_type(8))) short bf16x8;
typedef __attribute__((ext_vector_type(4))) float f32x4;
typedef __attribute__((ext_vector_type(2))) float f32x2;

#ifndef __has_builtin
#define __has_builtin(x) 0
#endif
#if __has_builtin(__builtin_amdgcn_cvt_pk_f32_fp8) && __has_builtin(__builtin_amdgcn_cvt_pk_fp8_f32)
#define HW_FP8 1
#else
#define HW_FP8 0
#endif

__device__ inline unsigned short f2bf(float f) {
    __hip_bfloat16 b = __float2bfloat16(f);
    return *reinterpret_cast<unsigned short*>(&b);
}
__device__ inline float bf2f(unsigned short u) {
    return __uint_as_float(((unsigned int)u) << 16);
}
__device__ inline void fp8x4_to_f32(unsigned int w, float* o) {
#if HW_FP8
    f32x2 lo = __builtin_amdgcn_cvt_pk_f32_fp8((int)w, false);
    f32x2 hi = __builtin_amdgcn_cvt_pk_f32_fp8((int)w, true);
    o[0] = lo.x; o[1] = lo.y; o[2] = hi.x; o[3] = hi.y;
#else
    #pragma unroll
    for (int c = 0; c < 4; ++c) {
        __hip_fp8_e4m3 q; q.__x = (__hip_fp8_storage_t)((w >> (8 * c)) & 0xFF);
        o[c] = (float)q;
    }
#endif
}
__device__ inline unsigned int f32x4_to_fp8(float a, float b, float c, float d) {
#if HW_FP8
    int p = __builtin_amdgcn_cvt_pk_fp8_f32(a, b, 0, false);
    p = __builtin_amdgcn_cvt_pk_fp8_f32(c, d, p, true);
    return (unsigned int)p;
#else
    __hip_fp8_e4m3 qa(a), qb(b), qc(c), qd(d);
    return (unsigned int)qa.__x | ((unsigned int)qb.__x << 8) |
           ((unsigned int)qc.__x << 16) | ((unsigned int)qd.__x << 24);
#endif
}

// ---------------------------------------------------------------------------
// Exclusive prefix scan over 256 LDS ints (256-thread blocks).
// ---------------------------------------------------------------------------
__device__ inline void block_excl_scan_256(const int* __restrict__ arr,
                                           int* __restrict__ excl,
                                           int* __restrict__ wsum, int tid)
{
    int lane = tid & 63, w = tid >> 6;
    int v = arr[tid];
    int inc = v;
    #pragma unroll
    for (int off = 1; off < 64; off <<= 1) {
        int t = __shfl_up(inc, off, 64);
        if (lane >= off) inc += t;
    }
    if (lane == 63) wsum[w] = inc;
    __syncthreads();
    if (tid == 0) {
        int s = 0;
        #pragma unroll
        for (int i = 0; i < 4; ++i) { int t = wsum[i]; wsum[i] = s; s += t; }
    }
    __syncthreads();
    excl[tid] = inc - v + wsum[w];
    __syncthreads();
}

// Same scan but callable from 1024-thread blocks (first 4 waves do the work;
// all threads participate in barriers).
__device__ inline void block_excl_scan_256_w1024(const int* __restrict__ arr,
                                                 int* __restrict__ excl,
                                                 int* __restrict__ wsum, int tid)
{
    int lane = tid & 63, w = tid >> 6;          // w in 0..15
    int v = (tid < 256) ? arr[tid] : 0;
    int inc = v;
    #pragma unroll
    for (int off = 1; off < 64; off <<= 1) {
        int t = __shfl_up(inc, off, 64);
        if (lane >= off) inc += t;
    }
    if (w < 4 && lane == 63) wsum[w] = inc;
    __syncthreads();
    if (tid == 0) {
        int s = 0;
        #pragma unroll
        for (int i = 0; i < 4; ++i) { int t = wsum[i]; wsum[i] = s; s += t; }
    }
    __syncthreads();
    if (tid < 256) excl[tid] = inc - v + wsum[w];
    __syncthreads();
}

// ---------------------------------------------------------------------------
// prep_kernel — three independent block ranges:
//   [0, cvtB)              : x -> xq (fp8 e4m3) AND xb (bf16)
//   [cvtB, cvtB+192)       : pack Wl1 / Wr1 / [Wl2|Wr2] into MFMA B-frag order
//   [cvtB+192, ...)        : bin_coarse — counting-sort pass A (dst>>8)
// ---------------------------------------------------------------------------
__global__ __launch_bounds__(256) void prep_kernel(
    const float* __restrict__ x, unsigned char* __restrict__ xq,
    unsigned short* __restrict__ xb,
    const float* __restrict__ Wl1, const float* __restrict__ Wr1,
    const float* __restrict__ Wl2, const float* __restrict__ Wr2,
    unsigned short* __restrict__ W1p, unsigned short* __restrict__ W2p,
    const int* __restrict__ ei, int* __restrict__ cursor,
    unsigned int* __restrict__ coarse,
    int total8, int cvtB, int E, int nb, int cap)
{
    __shared__ int hist[256], lstart[256], gbase[256], wsum[4];
    __shared__ unsigned int staged[4096];
    const int b = blockIdx.x;
    const int tid = threadIdx.x;

    if (b < cvtB) {
        int i = b * 256 + tid;
        if (i >= total8) return;
        float4 a = ((const float4*)x)[2 * i];
        float4 c = ((const float4*)x)[2 * i + 1];
        uint2 pk;
        pk.x = f32x4_to_fp8(a.x, a.y, a.z, a.w);
        pk.y = f32x4_to_fp8(c.x, c.y, c.z, c.w);
        *(uint2*)(xq + (size_t)i * 8) = pk;
        unsigned short t8[8];
        t8[0]=f2bf(a.x); t8[1]=f2bf(a.y); t8[2]=f2bf(a.z); t8[3]=f2bf(a.w);
        t8[4]=f2bf(c.x); t8[5]=f2bf(c.y); t8[6]=f2bf(c.z); t8[7]=f2bf(c.w);
        *(uint4*)(xb + (size_t)i * 8) = *(uint4*)t8;
        return;
    }
    if (b < cvtB + 192) {
        int region = (b - cvtB) >> 6;
        int idx = ((b - cvtB) & 63) * 256 + tid;   // 0..16383
        int k = idx >> 7, c = idx & 127;
        int d = ((k >> 5) * 8 + (c >> 4)) * 512 + ((k >> 3) & 3) * 128 + (c & 15) * 8 + (k & 7);
        if (region == 0)      W1p[d] = f2bf(Wl1[idx]);
        else if (region == 1) W1p[128 * 128 + d] = f2bf(Wr1[idx]);
        else {
            float v = (c < 64) ? Wl2[k * 64 + c] : Wr2[k * 64 + (c - 64)];
            W2p[d] = f2bf(v);
        }
        return;
    }

    // ---- bin_coarse ----
    const int chunkBase = (b - cvtB - 192) * 4096;
    hist[tid] = 0;
    __syncthreads();

    unsigned int rec[16]; int pos[16]; int bb[16];
    #pragma unroll
    for (int i = 0; i < 16; ++i) {
        int e = chunkBase + i * 256 + tid;
        if (e < E) {
            int s = ei[e], d = ei[E + e];
            rec[i] = ((unsigned int)d << 16) | (unsigned int)s;
            bb[i]  = d >> 8;
            pos[i] = atomicAdd(&hist[bb[i]], 1);
        } else bb[i] = -1;
    }
    __syncthreads();

    block_excl_scan_256(hist, lstart, wsum, tid);

    if (tid < nb) {
        int c = hist[tid];
        gbase[tid] = c ? atomicAdd(&cursor[tid], c) : 0;
    }
    __syncthreads();

    #pragma unroll
    for (int i = 0; i < 16; ++i)
        if (bb[i] >= 0) staged[lstart[bb[i]] + pos[i]] = rec[i];
    __syncthreads();

    int total = min(4096, E - chunkBase);
    for (int i = tid; i < total; i += 256) {
        unsigned int r = staged[i];
        int bk  = (int)(r >> 24);
        int gp  = gbase[bk] + (i - lstart[bk]);
        if (gp < cap) coarse[(size_t)bk * cap + gp] = r;
    }
}

// ---------------------------------------------------------------------------
// Counting sort pass B — 1024 THREADS/BLOCK. One block per coarse bucket.
// At 256 threads this was a serial chain of 16 hist + 16 scatter global-load
// iterations with only 196 blocks (<256 CUs, 60 idle) and 4 waves/block to
// overlap -> ~22us. 1024 threads quarter the serial depth (nIter 16->4) and
// give 16 waves/CU.
// ---------------------------------------------------------------------------
__global__ __launch_bounds__(1024) void bin_fine(
    const int* __restrict__ cursor, const unsigned int* __restrict__ coarse,
    unsigned short* __restrict__ sorted, int* __restrict__ deg,
    int* __restrict__ row_start, int n, int cap)
{
    __shared__ int hist[256], pstart[256], cur2[256], wsum[4];
    const int b = blockIdx.x, tid = threadIdx.x;
    const int cnt = min(cursor[b], cap);
    const unsigned int* src = coarse + (size_t)b * cap;

    if (tid < 256) hist[tid] = 0;
    __syncthreads();

    int nIter = (cnt + 1023) >> 10;
    for (int i = 0; i < nIter; ++i) {
        int idx = i * 1024 + tid;
        if (idx < cnt) atomicAdd(&hist[(src[idx] >> 16) & 255], 1);
    }
    __syncthreads();

    block_excl_scan_256_w1024(hist, pstart, wsum, tid);
    if (tid < 256) cur2[tid] = pstart[tid];
    __syncthreads();

    for (int i = 0; i < nIter; ++i) {
        int idx = i * 1024 + tid;
        if (idx < cnt) {
            unsigned int r = src[idx];
            int dl = (r >> 16) & 255;
            int p  = atomicAdd(&cur2[dl], 1);
            sorted[(size_t)b * cap + p] = (unsigned short)(r & 0xFFFFu);
        }
    }

    int node = b * 256 + tid;
    if (tid < 256 && node < n) {
        deg[node]       = hist[tid];
        row_start[node] = b * cap + pstart[tid];
    }
}

// ---------------------------------------------------------------------------
// GEMM1 fused with layer-1 gather — R4 structure (best measured).
//   32-row tiles, 1563 blocks. Each of 4 waves gathers 8 rows (8 lanes/row,
//   16B uint4/lane), tail-free masked batches of 8 + index prefetch; then
//   computes a 16-row x 64-col output quadrant (rg = wave>>1, ch = wave&1).
//   Wr-path A-frags read from pre-converted bf16 xb. BN partials: ROW-MAJOR
//   bn_part[blk][256].
// ---------------------------------------------------------------------------
__global__ __launch_bounds__(256) void gemm1_fused(
    const unsigned char* __restrict__ xq, const unsigned short* __restrict__ xb,
    const int* __restrict__ row_start, const int* __restrict__ deg,
    const unsigned short* __restrict__ sorted,
    const unsigned short* __restrict__ W1p, const float* __restrict__ bias,
    unsigned short* __restrict__ hb,
    float* __restrict__ bn_part, int n)
{
    __shared__ unsigned short G[32][136];
    __shared__ float red[2][2][128];

    const int block_row = blockIdx.x * 32;
    const int tid  = threadIdx.x;
    const int wave = tid >> 6;
    const int lane = tid & 63;
    const int q    = lane >> 4;
    const int m16  = lane & 15;
    const int rg   = wave >> 1;      // row group (16 rows)
    const int ch   = wave & 1;       // column half (64 cols)

    // ---- gather this wave's 8 rows into G ----
    {
        int sub = lane & 7, oct = lane >> 3;
        int lr = rg * 16 + ch * 8 + oct;
        int g  = block_row + lr;
        float acc[16];
        #pragma unroll
        for (int j = 0; j < 16; ++j) acc[j] = 0.f;
        int d = 0, base = 0;
        if (g < n) { base = row_start[g]; d = deg[g]; }
        int nb8 = (d + 7) >> 3;            // masked full batches, no tail
        int si[8];
        if (nb8 > 0) {
            #pragma unroll
            for (int u = 0; u < 8; ++u)
                si[u] = (int)sorted[base + (u < d ? u : 0)];
        }
        for (int b = 0; b < nb8; ++b) {
            uint4 raws[8];
            #pragma unroll
            for (int u = 0; u < 8; ++u)
                raws[u] = ((const uint4*)(xq + (size_t)si[u] * DIN))[sub];
            // prefetch next batch's indices while gathers are in flight
            if (b + 1 < nb8) {
                int t0n = (b + 1) * 8;
                #pragma unroll
                for (int u = 0; u < 8; ++u) {
                    int tt = t0n + u;
                    si[u] = (int)sorted[base + (tt < d ? tt : 0)];
                }
            }
            int t0 = b * 8;
            #pragma unroll
            for (int u = 0; u < 8; ++u) {
                float w8 = (t0 + u < d) ? 1.0f : 0.0f;
                const unsigned int* w = (const unsigned int*)&raws[u];
                #pragma unroll
                for (int c = 0; c < 4; ++c) {
                    float o4[4];
                    fp8x4_to_f32(w[c], o4);
                    acc[c*4+0] = fmaf(o4[0], w8, acc[c*4+0]);
                    acc[c*4+1] = fmaf(o4[1], w8, acc[c*4+1]);
                    acc[c*4+2] = fmaf(o4[2], w8, acc[c*4+2]);
                    acc[c*4+3] = fmaf(o4[3], w8, acc[c*4+3]);
                }
            }
        }
        float inv = 1.0f / fmaxf((float)d, 1.0f);
        unsigned short t16[16];
        #pragma unroll
        for (int j = 0; j < 16; ++j) t16[j] = f2bf(acc[j] * inv);
        *(uint4*)&G[lr][sub * 16]     = ((uint4*)t16)[0];
        *(uint4*)&G[lr][sub * 16 + 8] = ((uint4*)t16)[1];
    }
    __syncthreads();   // MFMA reads 16 rows written by two waves

    f32x4 acc[4];
    #pragma unroll
    for (int nt = 0; nt < 4; ++nt) acc[nt] = (f32x4){0.f, 0.f, 0.f, 0.f};

    const int grow = block_row + rg * 16 + m16;   // this lane's A row
    #pragma unroll
    for (int ks = 0; ks < 4; ++ks) {
        bf16x8 ag = *(const bf16x8*)&G[rg * 16 + m16][ks * 32 + q * 8];
        const unsigned short* wp0 = W1p + (size_t)ks * 8 * 512 + (size_t)ch * 4 * 512;   // Wl1
        #pragma unroll
        for (int nt = 0; nt < 4; ++nt) {
            bf16x8 b = *(const bf16x8*)(wp0 + nt * 512 + lane * 8);
            acc[nt] = __builtin_amdgcn_mfma_f32_16x16x32_bf16(ag, b, acc[nt], 0, 0, 0);
        }
        // X frag: direct bf16 load from xb (pre-converted in prep)
        uint4 raw = make_uint4(0u, 0u, 0u, 0u);
        if (grow < n)
            raw = *(const uint4*)(xb + (size_t)grow * DIN + ks * 32 + q * 8);
        bf16x8 ax = *(bf16x8*)&raw;
        const unsigned short* wp1 = W1p + (size_t)(4 + ks) * 8 * 512 + (size_t)ch * 4 * 512; // Wr1
        #pragma unroll
        for (int nt = 0; nt < 4; ++nt) {
            bf16x8 b = *(const bf16x8*)(wp1 + nt * 512 + lane * 8);
            acc[nt] = __builtin_amdgcn_mfma_f32_16x16x32_bf16(ax, b, acc[nt], 0, 0, 0);
        }
    }

    // ---- epilogue: bias, hb store, BN partials (row-major bn_part) ----
    float psum[4], psq[4];
    #pragma unroll
    for (int nt = 0; nt < 4; ++nt) {
        int col = (ch * 4 + nt) * 16 + m16;
        float bv = bias[col];
        float s = 0.f, ssq = 0.f;
        #pragma unroll
        for (int reg = 0; reg < 4; ++reg) {
            int g = block_row + rg * 16 + q * 4 + reg;
            float v = acc[nt][reg] + bv;
            if (g < n) {
                hb[(size_t)g * DH + col] = f2bf(v);
                s += v; ssq += v * v;
            }
        }
        psum[nt] = s; psq[nt] = ssq;
    }
    #pragma unroll
    for (int nt = 0; nt < 4; ++nt) {
        psum[nt] += __shfl_xor(psum[nt], 16, 64);
        psum[nt] += __shfl_xor(psum[nt], 32, 64);
        psq[nt]  += __shfl_xor(psq[nt], 16, 64);
        psq[nt]  += __shfl_xor(psq[nt], 32, 64);
    }
    if (lane < 16) {
        #pragma unroll
        for (int nt = 0; nt < 4; ++nt) {
            red[0][rg][(ch * 4 + nt) * 16 + lane] = psum[nt];
            red[1][rg][(ch * 4 + nt) * 16 + lane] = psq[nt];
        }
    }
    __syncthreads();
    if (tid < 128) {
        float s   = red[0][0][tid] + red[0][1][tid];
        float ssq = red[1][0][tid] + red[1][1][tid];
        bn_part[(size_t)blockIdx.x * 256 + tid]       = s;
        bn_part[(size_t)blockIdx.x * 256 + 128 + tid] = ssq;
    }
}

// ---------------------------------------------------------------------------
// bn_reduce: 64 blocks; block j sums rows j, j+64, ... of bn_part[nblk][256]
// (coalesced 1KB rows) and atomicAdds its 256 column partials into
// bn_out[256] (= bn_sum[128] ++ bn_sumsq[128], zero-initialized).
// ---------------------------------------------------------------------------
__global__ __launch_bounds__(256) void bn_reduce(
    const float* __restrict__ bn_part, float* __restrict__ bn_out, int nblk)
{
    const int tid = threadIdx.x;
    float s = 0.f;
    for (int r = blockIdx.x; r < nblk; r += 64)
        s += bn_part[(size_t)r * 256 + tid];
    atomicAdd(&bn_out[tid], s);
}

// ---------------------------------------------------------------------------
// GEMM2 (MFMA bf16): BN finalize in LDS; A-frags loaded directly from hb and
// BN+ReLU applied in registers (no LDS A tile).
// cols 0..63 -> P = a@Wl2 (bf16), cols 64..127 -> out = a@Wr2 + b2 (fp32).
// ---------------------------------------------------------------------------
__global__ __launch_bounds__(256) void gemm2p_mfma(
    const unsigned short* __restrict__ hb,
    const float* __restrict__ bn_sum, const float* __restrict__ bn_sumsq,
    const float* __restrict__ gamma, const float* __restrict__ beta,
    const unsigned short* __restrict__ W2p, const float* __restrict__ bias,
    unsigned short* __restrict__ P, float* __restrict__ out, int n)
{
    __shared__ float s_scale[128], s_shift[128];

    const int block_row = blockIdx.x * 64;
    const int tid  = threadIdx.x;
    const int wave = tid >> 6;
    const int lane = tid & 63;
    const int q    = lane >> 4;
    const int m16  = lane & 15;

    if (tid < 128) {
        float invN = 1.0f / (float)n;
        float mu  = bn_sum[tid] * invN;
        float var = bn_sumsq[tid] * invN - mu * mu;
        float sc  = gamma[tid] * rsqrtf(var + BN_EPS);
        s_scale[tid] = sc;
        s_shift[tid] = beta[tid] - mu * sc;
    }
    __syncthreads();

    f32x4 acc[8];
    #pragma unroll
    for (int nt = 0; nt < 8; ++nt) acc[nt] = (f32x4){0.f, 0.f, 0.f, 0.f};

    const int grow = block_row + wave * 16 + m16;
    #pragma unroll
    for (int ks = 0; ks < 4; ++ks) {
        bf16x8 a;
        {
            int kbase = ks * 32 + q * 8;
            float4 sc0 = *(const float4*)&s_scale[kbase];
            float4 sc1 = *(const float4*)&s_scale[kbase + 4];
            float4 sh0 = *(const float4*)&s_shift[kbase];
            float4 sh1 = *(const float4*)&s_shift[kbase + 4];
            unsigned short t[8] = {0,0,0,0,0,0,0,0};
            if (grow < n) {
                uint4 raw = *(const uint4*)(hb + (size_t)grow * DH + kbase);
                const unsigned short* u = (const unsigned short*)&raw;
                t[0] = f2bf(fmaxf(bf2f(u[0]) * sc0.x + sh0.x, 0.f));
                t[1] = f2bf(fmaxf(bf2f(u[1]) * sc0.y + sh0.y, 0.f));
                t[2] = f2bf(fmaxf(bf2f(u[2]) * sc0.z + sh0.z, 0.f));
                t[3] = f2bf(fmaxf(bf2f(u[3]) * sc0.w + sh0.w, 0.f));
                t[4] = f2bf(fmaxf(bf2f(u[4]) * sc1.x + sh1.x, 0.f));
                t[5] = f2bf(fmaxf(bf2f(u[5]) * sc1.y + sh1.y, 0.f));
                t[6] = f2bf(fmaxf(bf2f(u[6]) * sc1.z + sh1.z, 0.f));
                t[7] = f2bf(fmaxf(bf2f(u[7]) * sc1.w + sh1.w, 0.f));
            }
            a = *(bf16x8*)t;
        }
        const unsigned short* wp = W2p + (size_t)ks * 8 * 512;
        #pragma unroll
        for (int nt = 0; nt < 8; ++nt) {
            bf16x8 b = *(const bf16x8*)(wp + nt * 512 + lane * 8);
            acc[nt] = __builtin_amdgcn_mfma_f32_16x16x32_bf16(a, b, acc[nt], 0, 0, 0);
        }
    }

    #pragma unroll
    for (int nt = 0; nt < 4; ++nt) {
        int col = nt * 16 + m16;
        #pragma unroll
        for (int reg = 0; reg < 4; ++reg) {
            int g = block_row + wave * 16 + q * 4 + reg;
            if (g < n) P[(size_t)g * DOUTC + col] = f2bf(acc[nt][reg]);
        }
    }
    #pragma unroll
    for (int nt = 4; nt < 8; ++nt) {
        int col = (nt - 4) * 16 + m16;
        float bv = bias[col];
        #pragma unroll
        for (int reg = 0; reg < 4; ++reg) {
            int g = block_row + wave * 16 + q * 4 + reg;
            if (g < n) out[(size_t)g * DOUTC + col] = acc[nt][reg] + bv;
        }
    }
}

// ---------------------------------------------------------------------------
// Layer-2 gather-mean over bf16 P rows. 8 rows/wave, 8 lanes/row (R8/R1
// structure — best measured; R9's 16-lane batch-16 variant regressed).
// ---------------------------------------------------------------------------
__global__ __launch_bounds__(256) void agg_gather64_add(
    const int* __restrict__ row_start, const int* __restrict__ deg,
    const unsigned short* __restrict__ sorted, const unsigned short* __restrict__ P,
    float* __restrict__ out, int n)
{
    int wid  = (blockIdx.x * 256 + threadIdx.x) >> 6;
    int lane = threadIdx.x & 63;
    int sub = lane & 7, oct = lane >> 3;
    int r = wid * 8 + oct;
    if (r >= n) return;

    float acc[8];
    #pragma unroll
    for (int j = 0; j < 8; ++j) acc[j] = 0.f;

    int base = row_start[r];
    int d    = deg[r];
    int nb8  = (d + 7) >> 3;
    int si[8];
    if (nb8 > 0) {
        #pragma unroll
        for (int u = 0; u < 8; ++u)
            si[u] = (int)sorted[base + (u < d ? u : 0)];
    }
    for (int b = 0; b < nb8; ++b) {
        uint4 raws[8];
        #pragma unroll
        for (int u = 0; u < 8; ++u)
            raws[u] = ((const uint4*)(P + (size_t)si[u] * DOUTC))[sub];
        if (b + 1 < nb8) {
            int t0n = (b + 1) * 8;
            #pragma unroll
            for (int u = 0; u < 8; ++u) {
                int tt = t0n + u;
                si[u] = (int)sorted[base + (tt < d ? tt : 0)];
            }
        }
        int t0 = b * 8;
        #pragma unroll
        for (int u = 0; u < 8; ++u) {
            float w8 = (t0 + u < d) ? 1.0f : 0.0f;
            const unsigned short* us = (const unsigned short*)&raws[u];
            #pragma unroll
            for (int j = 0; j < 8; ++j) acc[j] = fmaf(bf2f(us[j]), w8, acc[j]);
        }
    }
    float inv = 1.0f / fmaxf((float)d, 1.0f);
    float* op = out + (size_t)r * DOUTC + sub * 8;
    float4 c0 = *(float4*)op;
    float4 c1 = *((float4*)op + 1);
    c0.x += acc[0] * inv; c0.y += acc[1] * inv;
    c0.z += acc[2] * inv; c0.w += acc[3] * inv;
    c1.x += acc[4] * inv; c1.y += acc[5] * inv;
    c1.z += acc[6] * inv; c1.w += acc[7] * inv;
    *(float4*)op = c0;
    *((float4*)op + 1) = c1;
}

// ---------------------------------------------------------------------------
extern "C" void kernel_launch(void* const* d_in, const int* in_sizes, int n_in,
                              void* d_out, int out_size, void* d_ws, size_t ws_size,
                              hipStream_t stream)
{
    const float* x     = (const float*)d_in[0];
    const int*   ei    = (const int*)  d_in[1];
    const float* Wl1   = (const float*)d_in[2];
    const float* Wr1   = (const float*)d_in[3];
    const float* b1    = (const float*)d_in[4];
    const float* gamma = (const float*)d_in[5];
    const float* beta  = (const float*)d_in[6];
    const float* Wl2   = (const float*)d_in[7];
    const float* Wr2   = (const float*)d_in[8];
    const float* b2    = (const float*)d_in[9];
    float*       out   = (float*)d_out;

    const int N = in_sizes[0] / DIN;      // 50000
    const int E = in_sizes[1] / 2;        // 800000

    const int NB  = (N + 255) >> 8;                       // coarse buckets
    int cap = (E / NB) * 3 / 2 + 256;
    cap = (cap + 255) & ~255;

    const int gemm1_blocks = (N + 31) / 32;               // 32-row tiles
    const int gemm2_blocks = (N + 63) / 64;

    // workspace layout (segments 16B-aligned-ish; all 4B aligned)
    float* bn_sum   = (float*)d_ws;                       // 128
    float* bn_sumsq = bn_sum + DH;                        // 128
    int* cursor     = (int*)(bn_sumsq + DH);              // 256
    int* deg        = cursor + 256;                       // N
    int* row_start  = deg + N;                            // N
    unsigned int* coarse   = (unsigned int*)(row_start + N);            // NB*cap
    unsigned short* sorted = (unsigned short*)(coarse + (size_t)NB * cap);
    unsigned short* hb     = sorted + (size_t)NB * cap;   // N*128 bf16
    unsigned short* P      = hb + (size_t)N * DH;         // N*64 bf16
    unsigned short* W1p    = P + (size_t)N * DOUTC;       // 256*128 bf16
    unsigned short* W2p    = W1p + 256 * 128;             // 128*128 bf16
    unsigned short* xb     = W2p + 128 * 128;             // N*128 bf16
    unsigned char*  xq     = (unsigned char*)(xb + (size_t)N * DIN); // N*128 fp8
    float* bn_part  = (float*)(xq + (size_t)N * DIN);     // gemm1_blocks*256

    // zero bn sums + coarse cursors (contiguous)
    hipMemsetAsync(bn_sum, 0, (2 * DH + 256) * sizeof(float), stream);

    dim3 blk(256);
    const int cvtB        = (N * DIN / 8 + 255) / 256;        // 3125
    const int binA_blocks = (E + 4095) / 4096;                // 196
    const int g64_blocks  = ((N + 7) / 8 + 3) / 4;

    // ---- prep: x-quantize(+bf16) | weight-pack | coarse-bin (one launch) ----
    prep_kernel<<<cvtB + 192 + binA_blocks, blk, 0, stream>>>(
        x, xq, xb, Wl1, Wr1, Wl2, Wr2, W1p, W2p,
        ei, cursor, coarse, N * DIN / 8, cvtB, E, NB, cap);

    // ---- counting sort pass B (1024-thread blocks) ----
    bin_fine<<<NB, dim3(1024), 0, stream>>>(cursor, coarse, sorted, deg,
                                            row_start, N, cap);

    // ---- layer 1: fused gather + GEMM + BN partials ----
    gemm1_fused<<<gemm1_blocks, blk, 0, stream>>>(xq, xb, row_start, deg, sorted,
                                                  W1p, b1, hb, bn_part, N);

    // ---- BN partial reduction (coalesced rows, spread atomics) ----
    bn_reduce<<<64, blk, 0, stream>>>(bn_part, bn_sum, gemm1_blocks);

    // ---- layer 2: BN finalize + ReLU + project ----
    gemm2p_mfma<<<gemm2_blocks, blk, 0, stream>>>(hb, bn_sum, bn_sumsq,
                                                  gamma, beta, W2p, b2, P, out, N);

    // ---- layer 2 aggregation ----
    agg_gather64_add<<<g64_blocks, blk, 0, stream>>>(row_start, deg, sorted,
                                                     P, out, N);
}

// Round 11
// 184.405 us; speedup vs baseline: 1.0649x; 1.0064x over previous
//
#include <hip/hip_runtime.h>
#include <hip/hip_bf16.h>
#include <hip/hip_fp8.h>

#define DIN   128
#define DH    128
#define DOUTC 64
#define BN_EPS 1e-5f

typedef __attribute__((ext_vector_type(8))) short bf16x8;
typedef __attribute__((ext_vector_type(4))) float f32x4;
typedef __attribute__((ext_vector_type(2))) float f32x2;

#ifndef __has_builtin
#define __has_builtin(x) 0
#endif
#if __has_builtin(__builtin_amdgcn_cvt_pk_f32_fp8) && __has_builtin(__builtin_amdgcn_cvt_pk_fp8_f32)
#define HW_FP8 1
#else
#define HW_FP8 0
#endif

__device__ inline unsigned short f2bf(float f) {
    __hip_bfloat16 b = __float2bfloat16(f);
    return *reinterpret_cast<unsigned short*>(&b);
}
__device__ inline float bf2f(unsigned short u) {
    return __uint_as_float(((unsigned int)u) << 16);
}
__device__ inline void fp8x4_to_f32(unsigned int w, float* o) {
#if HW_FP8
    f32x2 lo = __builtin_amdgcn_cvt_pk_f32_fp8((int)w, false);
    f32x2 hi = __builtin_amdgcn_cvt_pk_f32_fp8((int)w, true);
    o[0] = lo.x; o[1] = lo.y; o[2] = hi.x; o[3] = hi.y;
#else
    #pragma unroll
    for (int c = 0; c < 4; ++c) {
        __hip_fp8_e4m3 q; q.__x = (__hip_fp8_storage_t)((w >> (8 * c)) & 0xFF);
        o[c] = (float)q;
    }
#endif
}
__device__ inline unsigned int f32x4_to_fp8(float a, float b, float c, float d) {
#if HW_FP8
    int p = __builtin_amdgcn_cvt_pk_fp8_f32(a, b, 0, false);
    p = __builtin_amdgcn_cvt_pk_fp8_f32(c, d, p, true);
    return (unsigned int)p;
#else
    __hip_fp8_e4m3 qa(a), qb(b), qc(c), qd(d);
    return (unsigned int)qa.__x | ((unsigned int)qb.__x << 8) |
           ((unsigned int)qc.__x << 16) | ((unsigned int)qd.__x << 24);
#endif
}

// ---------------------------------------------------------------------------
// Exclusive prefix scan over 256 LDS ints (256-thread blocks).
// ---------------------------------------------------------------------------
__device__ inline void block_excl_scan_256(const int* __restrict__ arr,
                                           int* __restrict__ excl,
                                           int* __restrict__ wsum, int tid)
{
    int lane = tid & 63, w = tid >> 6;
    int v = arr[tid];
    int inc = v;
    #pragma unroll
    for (int off = 1; off < 64; off <<= 1) {
        int t = __shfl_up(inc, off, 64);
        if (lane >= off) inc += t;
    }
    if (lane == 63) wsum[w] = inc;
    __syncthreads();
    if (tid == 0) {
        int s = 0;
        #pragma unroll
        for (int i = 0; i < 4; ++i) { int t = wsum[i]; wsum[i] = s; s += t; }
    }
    __syncthreads();
    excl[tid] = inc - v + wsum[w];
    __syncthreads();
}

// Same scan but callable from 1024-thread blocks (first 4 waves do the work;
// all threads participate in barriers).
__device__ inline void block_excl_scan_256_w1024(const int* __restrict__ arr,
                                                 int* __restrict__ excl,
                                                 int* __restrict__ wsum, int tid)
{
    int lane = tid & 63, w = tid >> 6;          // w in 0..15
    int v = (tid < 256) ? arr[tid] : 0;
    int inc = v;
    #pragma unroll
    for (int off = 1; off < 64; off <<= 1) {
        int t = __shfl_up(inc, off, 64);
        if (lane >= off) inc += t;
    }
    if (w < 4 && lane == 63) wsum[w] = inc;
    __syncthreads();
    if (tid == 0) {
        int s = 0;
        #pragma unroll
        for (int i = 0; i < 4; ++i) { int t = wsum[i]; wsum[i] = s; s += t; }
    }
    __syncthreads();
    if (tid < 256) excl[tid] = inc - v + wsum[w];
    __syncthreads();
}

// ---------------------------------------------------------------------------
// prep_kernel — three independent block ranges, ORDERED so the long-latency
// bin_coarse chains start FIRST and hide under the convert blocks (they were
// last, serializing their ~8-10us tail after the convert work drained):
//   [0, binA)              : bin_coarse — counting-sort pass A (dst>>8)
//   [binA, binA+cvtB)      : x -> xq (fp8 e4m3) AND xb (bf16)
//   [binA+cvtB, +192)      : pack Wl1 / Wr1 / [Wl2|Wr2] into MFMA B-frag order
// ---------------------------------------------------------------------------
__global__ __launch_bounds__(256) void prep_kernel(
    const float* __restrict__ x, unsigned char* __restrict__ xq,
    unsigned short* __restrict__ xb,
    const float* __restrict__ Wl1, const float* __restrict__ Wr1,
    const float* __restrict__ Wl2, const float* __restrict__ Wr2,
    unsigned short* __restrict__ W1p, unsigned short* __restrict__ W2p,
    const int* __restrict__ ei, int* __restrict__ cursor,
    unsigned int* __restrict__ coarse,
    int total8, int binA, int cvtB, int E, int nb, int cap)
{
    __shared__ int hist[256], lstart[256], gbase[256], wsum[4];
    __shared__ unsigned int staged[4096];
    const int b = blockIdx.x;
    const int tid = threadIdx.x;

    if (b >= binA) {
        int b2 = b - binA;
        if (b2 < cvtB) {
            int i = b2 * 256 + tid;
            if (i >= total8) return;
            float4 a = ((const float4*)x)[2 * i];
            float4 c = ((const float4*)x)[2 * i + 1];
            uint2 pk;
            pk.x = f32x4_to_fp8(a.x, a.y, a.z, a.w);
            pk.y = f32x4_to_fp8(c.x, c.y, c.z, c.w);
            *(uint2*)(xq + (size_t)i * 8) = pk;
            unsigned short t8[8];
            t8[0]=f2bf(a.x); t8[1]=f2bf(a.y); t8[2]=f2bf(a.z); t8[3]=f2bf(a.w);
            t8[4]=f2bf(c.x); t8[5]=f2bf(c.y); t8[6]=f2bf(c.z); t8[7]=f2bf(c.w);
            *(uint4*)(xb + (size_t)i * 8) = *(uint4*)t8;
            return;
        }
        int region = (b2 - cvtB) >> 6;
        int idx = ((b2 - cvtB) & 63) * 256 + tid;   // 0..16383
        int k = idx >> 7, c = idx & 127;
        int d = ((k >> 5) * 8 + (c >> 4)) * 512 + ((k >> 3) & 3) * 128 + (c & 15) * 8 + (k & 7);
        if (region == 0)      W1p[d] = f2bf(Wl1[idx]);
        else if (region == 1) W1p[128 * 128 + d] = f2bf(Wr1[idx]);
        else {
            float v = (c < 64) ? Wl2[k * 64 + c] : Wr2[k * 64 + (c - 64)];
            W2p[d] = f2bf(v);
        }
        return;
    }

    // ---- bin_coarse (blocks [0, binA) — scheduled first) ----
    const int chunkBase = b * 4096;
    hist[tid] = 0;
    __syncthreads();

    unsigned int rec[16]; int pos[16]; int bb[16];
    #pragma unroll
    for (int i = 0; i < 16; ++i) {
        int e = chunkBase + i * 256 + tid;
        if (e < E) {
            int s = ei[e], d = ei[E + e];
            rec[i] = ((unsigned int)d << 16) | (unsigned int)s;
            bb[i]  = d >> 8;
            pos[i] = atomicAdd(&hist[bb[i]], 1);
        } else bb[i] = -1;
    }
    __syncthreads();

    block_excl_scan_256(hist, lstart, wsum, tid);

    if (tid < nb) {
        int c = hist[tid];
        gbase[tid] = c ? atomicAdd(&cursor[tid], c) : 0;
    }
    __syncthreads();

    #pragma unroll
    for (int i = 0; i < 16; ++i)
        if (bb[i] >= 0) staged[lstart[bb[i]] + pos[i]] = rec[i];
    __syncthreads();

    int total = min(4096, E - chunkBase);
    for (int i = tid; i < total; i += 256) {
        unsigned int r = staged[i];
        int bk  = (int)(r >> 24);
        int gp  = gbase[bk] + (i - lstart[bk]);
        if (gp < cap) coarse[(size_t)bk * cap + gp] = r;
    }
}

// ---------------------------------------------------------------------------
// Counting sort pass B — 1024 THREADS/BLOCK (R10 win: nIter 16->4).
// ---------------------------------------------------------------------------
__global__ __launch_bounds__(1024) void bin_fine(
    const int* __restrict__ cursor, const unsigned int* __restrict__ coarse,
    unsigned short* __restrict__ sorted, int* __restrict__ deg,
    int* __restrict__ row_start, int n, int cap)
{
    __shared__ int hist[256], pstart[256], cur2[256], wsum[4];
    const int b = blockIdx.x, tid = threadIdx.x;
    const int cnt = min(cursor[b], cap);
    const unsigned int* src = coarse + (size_t)b * cap;

    if (tid < 256) hist[tid] = 0;
    __syncthreads();

    int nIter = (cnt + 1023) >> 10;
    for (int i = 0; i < nIter; ++i) {
        int idx = i * 1024 + tid;
        if (idx < cnt) atomicAdd(&hist[(src[idx] >> 16) & 255], 1);
    }
    __syncthreads();

    block_excl_scan_256_w1024(hist, pstart, wsum, tid);
    if (tid < 256) cur2[tid] = pstart[tid];
    __syncthreads();

    for (int i = 0; i < nIter; ++i) {
        int idx = i * 1024 + tid;
        if (idx < cnt) {
            unsigned int r = src[idx];
            int dl = (r >> 16) & 255;
            int p  = atomicAdd(&cur2[dl], 1);
            sorted[(size_t)b * cap + p] = (unsigned short)(r & 0xFFFFu);
        }
    }

    int node = b * 256 + tid;
    if (tid < 256 && node < n) {
        deg[node]       = hist[tid];
        row_start[node] = b * cap + pstart[tid];
    }
}

// ---------------------------------------------------------------------------
// GEMM1 fused with layer-1 gather — R4 structure (best measured).
//   32-row tiles, 1563 blocks. Each of 4 waves gathers 8 rows (8 lanes/row,
//   16B uint4/lane), tail-free masked batches of 8 + index prefetch; then
//   computes a 16-row x 64-col output quadrant (rg = wave>>1, ch = wave&1).
//   Wr-path A-frags read from pre-converted bf16 xb. BN partials: ROW-MAJOR
//   bn_part[blk][256].
// ---------------------------------------------------------------------------
__global__ __launch_bounds__(256) void gemm1_fused(
    const unsigned char* __restrict__ xq, const unsigned short* __restrict__ xb,
    const int* __restrict__ row_start, const int* __restrict__ deg,
    const unsigned short* __restrict__ sorted,
    const unsigned short* __restrict__ W1p, const float* __restrict__ bias,
    unsigned short* __restrict__ hb,
    float* __restrict__ bn_part, int n)
{
    __shared__ unsigned short G[32][136];
    __shared__ float red[2][2][128];

    const int block_row = blockIdx.x * 32;
    const int tid  = threadIdx.x;
    const int wave = tid >> 6;
    const int lane = tid & 63;
    const int q    = lane >> 4;
    const int m16  = lane & 15;
    const int rg   = wave >> 1;      // row group (16 rows)
    const int ch   = wave & 1;       // column half (64 cols)

    // ---- gather this wave's 8 rows into G ----
    {
        int sub = lane & 7, oct = lane >> 3;
        int lr = rg * 16 + ch * 8 + oct;
        int g  = block_row + lr;
        float acc[16];
        #pragma unroll
        for (int j = 0; j < 16; ++j) acc[j] = 0.f;
        int d = 0, base = 0;
        if (g < n) { base = row_start[g]; d = deg[g]; }
        int nb8 = (d + 7) >> 3;            // masked full batches, no tail
        int si[8];
        if (nb8 > 0) {
            #pragma unroll
            for (int u = 0; u < 8; ++u)
                si[u] = (int)sorted[base + (u < d ? u : 0)];
        }
        for (int b = 0; b < nb8; ++b) {
            uint4 raws[8];
            #pragma unroll
            for (int u = 0; u < 8; ++u)
                raws[u] = ((const uint4*)(xq + (size_t)si[u] * DIN))[sub];
            // prefetch next batch's indices while gathers are in flight
            if (b + 1 < nb8) {
                int t0n = (b + 1) * 8;
                #pragma unroll
                for (int u = 0; u < 8; ++u) {
                    int tt = t0n + u;
                    si[u] = (int)sorted[base + (tt < d ? tt : 0)];
                }
            }
            int t0 = b * 8;
            #pragma unroll
            for (int u = 0; u < 8; ++u) {
                float w8 = (t0 + u < d) ? 1.0f : 0.0f;
                const unsigned int* w = (const unsigned int*)&raws[u];
                #pragma unroll
                for (int c = 0; c < 4; ++c) {
                    float o4[4];
                    fp8x4_to_f32(w[c], o4);
                    acc[c*4+0] = fmaf(o4[0], w8, acc[c*4+0]);
                    acc[c*4+1] = fmaf(o4[1], w8, acc[c*4+1]);
                    acc[c*4+2] = fmaf(o4[2], w8, acc[c*4+2]);
                    acc[c*4+3] = fmaf(o4[3], w8, acc[c*4+3]);
                }
            }
        }
        float inv = 1.0f / fmaxf((float)d, 1.0f);
        unsigned short t16[16];
        #pragma unroll
        for (int j = 0; j < 16; ++j) t16[j] = f2bf(acc[j] * inv);
        *(uint4*)&G[lr][sub * 16]     = ((uint4*)t16)[0];
        *(uint4*)&G[lr][sub * 16 + 8] = ((uint4*)t16)[1];
    }
    __syncthreads();   // MFMA reads 16 rows written by two waves

    f32x4 acc[4];
    #pragma unroll
    for (int nt = 0; nt < 4; ++nt) acc[nt] = (f32x4){0.f, 0.f, 0.f, 0.f};

    const int grow = block_row + rg * 16 + m16;   // this lane's A row
    #pragma unroll
    for (int ks = 0; ks < 4; ++ks) {
        bf16x8 ag = *(const bf16x8*)&G[rg * 16 + m16][ks * 32 + q * 8];
        const unsigned short* wp0 = W1p + (size_t)ks * 8 * 512 + (size_t)ch * 4 * 512;   // Wl1
        #pragma unroll
        for (int nt = 0; nt < 4; ++nt) {
            bf16x8 b = *(const bf16x8*)(wp0 + nt * 512 + lane * 8);
            acc[nt] = __builtin_amdgcn_mfma_f32_16x16x32_bf16(ag, b, acc[nt], 0, 0, 0);
        }
        // X frag: direct bf16 load from xb (pre-converted in prep)
        uint4 raw = make_uint4(0u, 0u, 0u, 0u);
        if (grow < n)
            raw = *(const uint4*)(xb + (size_t)grow * DIN + ks * 32 + q * 8);
        bf16x8 ax = *(bf16x8*)&raw;
        const unsigned short* wp1 = W1p + (size_t)(4 + ks) * 8 * 512 + (size_t)ch * 4 * 512; // Wr1
        #pragma unroll
        for (int nt = 0; nt < 4; ++nt) {
            bf16x8 b = *(const bf16x8*)(wp1 + nt * 512 + lane * 8);
            acc[nt] = __builtin_amdgcn_mfma_f32_16x16x32_bf16(ax, b, acc[nt], 0, 0, 0);
        }
    }

    // ---- epilogue: bias, hb store, BN partials (row-major bn_part) ----
    float psum[4], psq[4];
    #pragma unroll
    for (int nt = 0; nt < 4; ++nt) {
        int col = (ch * 4 + nt) * 16 + m16;
        float bv = bias[col];
        float s = 0.f, ssq = 0.f;
        #pragma unroll
        for (int reg = 0; reg < 4; ++reg) {
            int g = block_row + rg * 16 + q * 4 + reg;
            float v = acc[nt][reg] + bv;
            if (g < n) {
                hb[(size_t)g * DH + col] = f2bf(v);
                s += v; ssq += v * v;
            }
        }
        psum[nt] = s; psq[nt] = ssq;
    }
    #pragma unroll
    for (int nt = 0; nt < 4; ++nt) {
        psum[nt] += __shfl_xor(psum[nt], 16, 64);
        psum[nt] += __shfl_xor(psum[nt], 32, 64);
        psq[nt]  += __shfl_xor(psq[nt], 16, 64);
        psq[nt]  += __shfl_xor(psq[nt], 32, 64);
    }
    if (lane < 16) {
        #pragma unroll
        for (int nt = 0; nt < 4; ++nt) {
            red[0][rg][(ch * 4 + nt) * 16 + lane] = psum[nt];
            red[1][rg][(ch * 4 + nt) * 16 + lane] = psq[nt];
        }
    }
    __syncthreads();
    if (tid < 128) {
        float s   = red[0][0][tid] + red[0][1][tid];
        float ssq = red[1][0][tid] + red[1][1][tid];
        bn_part[(size_t)blockIdx.x * 256 + tid]       = s;
        bn_part[(size_t)blockIdx.x * 256 + 128 + tid] = ssq;
    }
}

// ---------------------------------------------------------------------------
// bn_reduce: 64 blocks; block j sums rows j, j+64, ... of bn_part[nblk][256]
// (coalesced 1KB rows) and atomicAdds its 256 column partials into
// bn_out[256] (= bn_sum[128] ++ bn_sumsq[128], zero-initialized).
// ---------------------------------------------------------------------------
__global__ __launch_bounds__(256) void bn_reduce(
    const float* __restrict__ bn_part, float* __restrict__ bn_out, int nblk)
{
    const int tid = threadIdx.x;
    float s = 0.f;
    for (int r = blockIdx.x; r < nblk; r += 64)
        s += bn_part[(size_t)r * 256 + tid];
    atomicAdd(&bn_out[tid], s);
}

// ---------------------------------------------------------------------------
// GEMM2 (MFMA bf16) — 32-ROW TILES (gemm1's proven decomposition applied):
// 1563 blocks; wave (rg = wave>>1, ch = wave&1) computes 16 rows x 64 cols.
// ch=0 -> P = a@Wl2 (bf16), ch=1 -> out = a@Wr2 + b2 (fp32). acc[4] instead
// of acc[8] (~50 VGPR vs ~100 -> 8 waves/SIMD vs ~4; 64-row version was
// 782 blocks at ~3 blocks/CU). hb rows re-read by the ch=1 wave are L2 hits.
// BN finalize in LDS; BN+ReLU applied in registers (no LDS A tile).
// ---------------------------------------------------------------------------
__global__ __launch_bounds__(256) void gemm2p_mfma(
    const unsigned short* __restrict__ hb,
    const float* __restrict__ bn_sum, const float* __restrict__ bn_sumsq,
    const float* __restrict__ gamma, const float* __restrict__ beta,
    const unsigned short* __restrict__ W2p, const float* __restrict__ bias,
    unsigned short* __restrict__ P, float* __restrict__ out, int n)
{
    __shared__ float s_scale[128], s_shift[128];

    const int block_row = blockIdx.x * 32;
    const int tid  = threadIdx.x;
    const int wave = tid >> 6;
    const int lane = tid & 63;
    const int q    = lane >> 4;
    const int m16  = lane & 15;
    const int rg   = wave >> 1;      // row group (16 rows)
    const int ch   = wave & 1;       // 0 -> P cols, 1 -> out cols

    if (tid < 128) {
        float invN = 1.0f / (float)n;
        float mu  = bn_sum[tid] * invN;
        float var = bn_sumsq[tid] * invN - mu * mu;
        float sc  = gamma[tid] * rsqrtf(var + BN_EPS);
        s_scale[tid] = sc;
        s_shift[tid] = beta[tid] - mu * sc;
    }
    __syncthreads();

    f32x4 acc[4];
    #pragma unroll
    for (int nt = 0; nt < 4; ++nt) acc[nt] = (f32x4){0.f, 0.f, 0.f, 0.f};

    const int grow = block_row + rg * 16 + m16;
    #pragma unroll
    for (int ks = 0; ks < 4; ++ks) {
        bf16x8 a;
        {
            int kbase = ks * 32 + q * 8;
            float4 sc0 = *(const float4*)&s_scale[kbase];
            float4 sc1 = *(const float4*)&s_scale[kbase + 4];
            float4 sh0 = *(const float4*)&s_shift[kbase];
            float4 sh1 = *(const float4*)&s_shift[kbase + 4];
            unsigned short t[8] = {0,0,0,0,0,0,0,0};
            if (grow < n) {
                uint4 raw = *(const uint4*)(hb + (size_t)grow * DH + kbase);
                const unsigned short* u = (const unsigned short*)&raw;
                t[0] = f2bf(fmaxf(bf2f(u[0]) * sc0.x + sh0.x, 0.f));
                t[1] = f2bf(fmaxf(bf2f(u[1]) * sc0.y + sh0.y, 0.f));
                t[2] = f2bf(fmaxf(bf2f(u[2]) * sc0.z + sh0.z, 0.f));
                t[3] = f2bf(fmaxf(bf2f(u[3]) * sc0.w + sh0.w, 0.f));
                t[4] = f2bf(fmaxf(bf2f(u[4]) * sc1.x + sh1.x, 0.f));
                t[5] = f2bf(fmaxf(bf2f(u[5]) * sc1.y + sh1.y, 0.f));
                t[6] = f2bf(fmaxf(bf2f(u[6]) * sc1.z + sh1.z, 0.f));
                t[7] = f2bf(fmaxf(bf2f(u[7]) * sc1.w + sh1.w, 0.f));
            }
            a = *(bf16x8*)t;
        }
        const unsigned short* wp = W2p + (size_t)ks * 8 * 512 + (size_t)ch * 4 * 512;
        #pragma unroll
        for (int nt = 0; nt < 4; ++nt) {
            bf16x8 b = *(const bf16x8*)(wp + nt * 512 + lane * 8);
            acc[nt] = __builtin_amdgcn_mfma_f32_16x16x32_bf16(a, b, acc[nt], 0, 0, 0);
        }
    }

    if (ch == 0) {
        #pragma unroll
        for (int nt = 0; nt < 4; ++nt) {
            int col = nt * 16 + m16;
            #pragma unroll
            for (int reg = 0; reg < 4; ++reg) {
                int g = block_row + rg * 16 + q * 4 + reg;
                if (g < n) P[(size_t)g * DOUTC + col] = f2bf(acc[nt][reg]);
            }
        }
    } else {
        #pragma unroll
        for (int nt = 0; nt < 4; ++nt) {
            int col = nt * 16 + m16;
            float bv = bias[col];
            #pragma unroll
            for (int reg = 0; reg < 4; ++reg) {
                int g = block_row + rg * 16 + q * 4 + reg;
                if (g < n) out[(size_t)g * DOUTC + col] = acc[nt][reg] + bv;
            }
        }
    }
}

// ---------------------------------------------------------------------------
// Layer-2 gather-mean over bf16 P rows. 8 rows/wave, 8 lanes/row (R8/R1
// structure — best measured; R9's 16-lane batch-16 variant regressed).
// ---------------------------------------------------------------------------
__global__ __launch_bounds__(256) void agg_gather64_add(
    const int* __restrict__ row_start, const int* __restrict__ deg,
    const unsigned short* __restrict__ sorted, const unsigned short* __restrict__ P,
    float* __restrict__ out, int n)
{
    int wid  = (blockIdx.x * 256 + threadIdx.x) >> 6;
    int lane = threadIdx.x & 63;
    int sub = lane & 7, oct = lane >> 3;
    int r = wid * 8 + oct;
    if (r >= n) return;

    float acc[8];
    #pragma unroll
    for (int j = 0; j < 8; ++j) acc[j] = 0.f;

    int base = row_start[r];
    int d    = deg[r];
    int nb8  = (d + 7) >> 3;
    int si[8];
    if (nb8 > 0) {
        #pragma unroll
        for (int u = 0; u < 8; ++u)
            si[u] = (int)sorted[base + (u < d ? u : 0)];
    }
    for (int b = 0; b < nb8; ++b) {
        uint4 raws[8];
        #pragma unroll
        for (int u = 0; u < 8; ++u)
            raws[u] = ((const uint4*)(P + (size_t)si[u] * DOUTC))[sub];
        if (b + 1 < nb8) {
            int t0n = (b + 1) * 8;
            #pragma unroll
            for (int u = 0; u < 8; ++u) {
                int tt = t0n + u;
                si[u] = (int)sorted[base + (tt < d ? tt : 0)];
            }
        }
        int t0 = b * 8;
        #pragma unroll
        for (int u = 0; u < 8; ++u) {
            float w8 = (t0 + u < d) ? 1.0f : 0.0f;
            const unsigned short* us = (const unsigned short*)&raws[u];
            #pragma unroll
            for (int j = 0; j < 8; ++j) acc[j] = fmaf(bf2f(us[j]), w8, acc[j]);
        }
    }
    float inv = 1.0f / fmaxf((float)d, 1.0f);
    float* op = out + (size_t)r * DOUTC + sub * 8;
    float4 c0 = *(float4*)op;
    float4 c1 = *((float4*)op + 1);
    c0.x += acc[0] * inv; c0.y += acc[1] * inv;
    c0.z += acc[2] * inv; c0.w += acc[3] * inv;
    c1.x += acc[4] * inv; c1.y += acc[5] * inv;
    c1.z += acc[6] * inv; c1.w += acc[7] * inv;
    *(float4*)op = c0;
    *((float4*)op + 1) = c1;
}

// ---------------------------------------------------------------------------
extern "C" void kernel_launch(void* const* d_in, const int* in_sizes, int n_in,
                              void* d_out, int out_size, void* d_ws, size_t ws_size,
                              hipStream_t stream)
{
    const float* x     = (const float*)d_in[0];
    const int*   ei    = (const int*)  d_in[1];
    const float* Wl1   = (const float*)d_in[2];
    const float* Wr1   = (const float*)d_in[3];
    const float* b1    = (const float*)d_in[4];
    const float* gamma = (const float*)d_in[5];
    const float* beta  = (const float*)d_in[6];
    const float* Wl2   = (const float*)d_in[7];
    const float* Wr2   = (const float*)d_in[8];
    const float* b2    = (const float*)d_in[9];
    float*       out   = (float*)d_out;

    const int N = in_sizes[0] / DIN;      // 50000
    const int E = in_sizes[1] / 2;        // 800000

    const int NB  = (N + 255) >> 8;                       // coarse buckets
    int cap = (E / NB) * 3 / 2 + 256;
    cap = (cap + 255) & ~255;

    const int gemm1_blocks = (N + 31) / 32;               // 32-row tiles
    const int gemm2_blocks = (N + 31) / 32;               // 32-row tiles

    // workspace layout (segments 16B-aligned-ish; all 4B aligned)
    float* bn_sum   = (float*)d_ws;                       // 128
    float* bn_sumsq = bn_sum + DH;                        // 128
    int* cursor     = (int*)(bn_sumsq + DH);              // 256
    int* deg        = cursor + 256;                       // N
    int* row_start  = deg + N;                            // N
    unsigned int* coarse   = (unsigned int*)(row_start + N);            // NB*cap
    unsigned short* sorted = (unsigned short*)(coarse + (size_t)NB * cap);
    unsigned short* hb     = sorted + (size_t)NB * cap;   // N*128 bf16
    unsigned short* P      = hb + (size_t)N * DH;         // N*64 bf16
    unsigned short* W1p    = P + (size_t)N * DOUTC;       // 256*128 bf16
    unsigned short* W2p    = W1p + 256 * 128;             // 128*128 bf16
    unsigned short* xb     = W2p + 128 * 128;             // N*128 bf16
    unsigned char*  xq     = (unsigned char*)(xb + (size_t)N * DIN); // N*128 fp8
    float* bn_part  = (float*)(xq + (size_t)N * DIN);     // gemm1_blocks*256

    // zero bn sums + coarse cursors (contiguous)
    hipMemsetAsync(bn_sum, 0, (2 * DH + 256) * sizeof(float), stream);

    dim3 blk(256);
    const int cvtB        = (N * DIN / 8 + 255) / 256;        // 3125
    const int binA_blocks = (E + 4095) / 4096;                // 196
    const int g64_blocks  = ((N + 7) / 8 + 3) / 4;

    // ---- prep: coarse-bin FIRST | x-quantize(+bf16) | weight-pack ----
    prep_kernel<<<binA_blocks + cvtB + 192, blk, 0, stream>>>(
        x, xq, xb, Wl1, Wr1, Wl2, Wr2, W1p, W2p,
        ei, cursor, coarse, N * DIN / 8, binA_blocks, cvtB, E, NB, cap);

    // ---- counting sort pass B (1024-thread blocks) ----
    bin_fine<<<NB, dim3(1024), 0, stream>>>(cursor, coarse, sorted, deg,
                                            row_start, N, cap);

    // ---- layer 1: fused gather + GEMM + BN partials ----
    gemm1_fused<<<gemm1_blocks, blk, 0, stream>>>(xq, xb, row_start, deg, sorted,
                                                  W1p, b1, hb, bn_part, N);

    // ---- BN partial reduction (coalesced rows, spread atomics) ----
    bn_reduce<<<64, blk, 0, stream>>>(bn_part, bn_sum, gemm1_blocks);

    // ---- layer 2: BN finalize + ReLU + project (32-row tiles) ----
    gemm2p_mfma<<<gemm2_blocks, blk, 0, stream>>>(hb, bn_sum, bn_sumsq,
                                                  gamma, beta, W2p, b2, P, out, N);

    // ---- layer 2 aggregation ----
    agg_gather64_add<<<g64_blocks, blk, 0, stream>>>(row_start, deg, sorted,
                                                     P, out, N);
}